// Round 5
// baseline (505.940 us; speedup 1.0000x reference)
//
#include <hip/hip_runtime.h>
#include <hip/hip_bf16.h>

#define N_NODES 8192
#define MAXD 128

typedef __attribute__((ext_vector_type(8))) __bf16 bf16x8;
typedef __attribute__((ext_vector_type(4))) float floatx4;
typedef float __attribute__((ext_vector_type(4))) f32x4;

__device__ __forceinline__ void async16(void* lds, const void* g) {
  __builtin_amdgcn_global_load_lds((const __attribute__((address_space(1))) void*)g,
                                   (__attribute__((address_space(3))) void*)lds, 16, 0, 0);
}

__device__ __forceinline__ float bfu(unsigned short u) {
  union { unsigned int i; float f; } c; c.i = (unsigned int)u << 16; return c.f;
}

// ---------------- prep weights only: transposes, hi/lo splits, stats zero ----------------
__global__ __launch_bounds__(256) void prep_w(const float* __restrict__ mlp_W1,
                                              const float* __restrict__ mlp_W2,
                                              const float* __restrict__ att_W1,
                                              const float* __restrict__ pred_W,
                                              const float* __restrict__ mask_W1,
                                              __hip_bfloat16* __restrict__ Wt1,
                                              __hip_bfloat16* __restrict__ Wt2,
                                              __hip_bfloat16* __restrict__ attHi,
                                              __hip_bfloat16* __restrict__ attLo,
                                              __hip_bfloat16* __restrict__ predWt,
                                              __hip_bfloat16* __restrict__ maskHi,
                                              __hip_bfloat16* __restrict__ maskLo,
                                              float* __restrict__ stats) {
  __shared__ float tile[32][33];
  const int blk = blockIdx.x, tid = threadIdx.x;
  if (blk < 480) {
    const int tx = tid & 31, ty = tid >> 5;
    const float* in; __hip_bfloat16* oh; __hip_bfloat16* ol = nullptr;
    int K, N, kt, nt;
    if (blk < 384) {
      const int z = blk / 64, rem = blk % 64; kt = rem / 8; nt = rem % 8; K = 256; N = 256;
      in = z < 3 ? mlp_W1 + (size_t)z * 65536 : mlp_W2 + (size_t)(z - 3) * 65536;
      oh = z < 3 ? Wt1 + (size_t)z * 65536 : Wt2 + (size_t)(z - 3) * 65536;
    } else if (blk < 432) {
      const int i = blk - 384, z = i / 16, rem = i % 16; kt = rem / 2; nt = rem & 1;
      K = 256; N = 64;
      in = att_W1 + (size_t)z * 16384; oh = attHi + (size_t)z * 16384;
      ol = attLo + (size_t)z * 16384;
    } else {
      const int i = blk - 432; kt = i / 2; nt = i & 1; K = 768; N = 64;
      in = pred_W; oh = predWt;
    }
    const int k0 = kt * 32, n0 = nt * 32;
#pragma unroll
    for (int r = 0; r < 4; ++r)
      tile[ty + r * 8][tx] = in[(size_t)(k0 + ty + r * 8) * N + n0 + tx];
    __syncthreads();
#pragma unroll
    for (int r = 0; r < 4; ++r) {
      const float v = tile[tx][ty + r * 8];
      const __hip_bfloat16 hi = __float2bfloat16(v);
      oh[(size_t)(n0 + ty + r * 8) * K + k0 + tx] = hi;
      if (ol)
        ol[(size_t)(n0 + ty + r * 8) * K + k0 + tx] =
            __float2bfloat16(v - __bfloat162float(hi));
    }
  } else if (blk == 480) {
    for (int i = tid; i < 16384; i += 256) {
      const int n = i >> 8, k = i & 255;
      const float v = (n < 54) ? mask_W1[k * 54 + n] : 0.f;
      const __hip_bfloat16 hi = __float2bfloat16(v);
      maskHi[n * 256 + k] = hi;
      maskLo[n * 256 + k] = __float2bfloat16(v - __bfloat162float(hi));
    }
  } else {
    for (int i = tid; i < 1536; i += 256) stats[i] = 0.f;
  }
}

// ---------------- mega-kernel: e-MLP(x) + mask-MLP(x) + x->bf16 + CSR scan, one dispatch ----------------
// blocks 0..255: att e-MLP (32 nodes each); 256..511: mask MLP; 512..1023: x->hbHi; 1024..9215: CSR scan.
__global__ __launch_bounds__(256) void scan_emlp(
    const float* __restrict__ x, const float* __restrict__ graph,
    const __hip_bfloat16* __restrict__ aHi, const __hip_bfloat16* __restrict__ aLo,
    const float* __restrict__ ab1, const float* __restrict__ aw2, const float* __restrict__ ab2,
    const __hip_bfloat16* __restrict__ mHi, const __hip_bfloat16* __restrict__ mLo,
    const float* __restrict__ mb1, const float* __restrict__ mw2, const float* __restrict__ mb2,
    __hip_bfloat16* __restrict__ hbHi, float* __restrict__ evec, float* __restrict__ maskL,
    int* __restrict__ col_idx, int* __restrict__ deg) {
  __shared__ union {
    struct { __hip_bfloat16 Hi[32][264]; __hip_bfloat16 Lo[32][264]; } s;
    float red[64][36];
    int cnt;
  } sm;
  const int blk = blockIdx.x, tid = threadIdx.x;
  if (blk >= 1024) {  // CSR scan: block per row, nontemporal stream
    const int i = blk - 1024;
    if (tid == 0) sm.cnt = 0;
    __syncthreads();
    const f32x4* row = (const f32x4*)(graph + (size_t)i * N_NODES);
#pragma unroll
    for (int it = 0; it < 8; ++it) {
      const int idx = it * 256 + tid;
      f32x4 v = __builtin_nontemporal_load(&row[idx]);
      if (v.x > 0.f) { int p = atomicAdd(&sm.cnt, 1); if (p < MAXD) col_idx[(size_t)i * MAXD + p] = idx * 4 + 0; }
      if (v.y > 0.f) { int p = atomicAdd(&sm.cnt, 1); if (p < MAXD) col_idx[(size_t)i * MAXD + p] = idx * 4 + 1; }
      if (v.z > 0.f) { int p = atomicAdd(&sm.cnt, 1); if (p < MAXD) col_idx[(size_t)i * MAXD + p] = idx * 4 + 2; }
      if (v.w > 0.f) { int p = atomicAdd(&sm.cnt, 1); if (p < MAXD) col_idx[(size_t)i * MAXD + p] = idx * 4 + 3; }
    }
    __syncthreads();
    if (tid == 0) deg[i] = sm.cnt < MAXD ? sm.cnt : MAXD;
    return;
  }
  if (blk >= 512) {  // x -> hbHi (bf16)
    const float4* xv = (const float4*)x;
    const int base = (blk - 512) * 1024;
#pragma unroll
    for (int it = 0; it < 4; ++it) {
      const int i = base + it * 256 + tid;
      const float4 v = xv[i];
      union { __hip_bfloat16 h[4]; short4 s4; } ph;
      ph.h[0] = __float2bfloat16(v.x); ph.h[1] = __float2bfloat16(v.y);
      ph.h[2] = __float2bfloat16(v.z); ph.h[3] = __float2bfloat16(v.w);
      ((short4*)hbHi)[i] = ph.s4;
    }
    return;
  }
  // ---- e-MLP roles: stage 32 rows of x as hi/lo bf16 in LDS, 3-MFMA split GEMM ----
  const bool is_mask = blk >= 256;
  const int m0 = (is_mask ? blk - 256 : blk) * 32;
  const int w = tid >> 6, lane = tid & 63;
  const int q = lane >> 4, l15 = lane & 15;
  {
    const float4* xv = (const float4*)x;
#pragma unroll
    for (int t = 0; t < 8; ++t) {
      const int i = t * 256 + tid;
      const int row = i >> 6, c4 = i & 63;
      const float4 v = xv[(size_t)(m0 + row) * 64 + c4];
      union { __hip_bfloat16 h[4]; short4 s4; } ph, pl;
      ph.h[0] = __float2bfloat16(v.x); ph.h[1] = __float2bfloat16(v.y);
      ph.h[2] = __float2bfloat16(v.z); ph.h[3] = __float2bfloat16(v.w);
      pl.h[0] = __float2bfloat16(v.x - __bfloat162float(ph.h[0]));
      pl.h[1] = __float2bfloat16(v.y - __bfloat162float(ph.h[1]));
      pl.h[2] = __float2bfloat16(v.z - __bfloat162float(ph.h[2]));
      pl.h[3] = __float2bfloat16(v.w - __bfloat162float(ph.h[3]));
      *(short4*)&sm.s.Hi[row][c4 * 4] = ph.s4;
      *(short4*)&sm.s.Lo[row][c4 * 4] = pl.s4;
    }
  }
  __syncthreads();
  const __hip_bfloat16* Whi = is_mask ? mHi : aHi;
  const __hip_bfloat16* Wlo = is_mask ? mLo : aLo;
  const int n = w * 16 + l15;
  floatx4 acc[2] = {};
  for (int kc = 0; kc < 8; ++kc) {
    const int kb = kc * 32 + q * 8;
    const bf16x8 bHi = *(const bf16x8*)(Whi + (size_t)n * 256 + kb);
    const bf16x8 bLo = *(const bf16x8*)(Wlo + (size_t)n * 256 + kb);
#pragma unroll
    for (int mt = 0; mt < 2; ++mt) {
      const bf16x8 ah = *(const bf16x8*)&sm.s.Hi[mt * 16 + l15][kb];
      const bf16x8 al = *(const bf16x8*)&sm.s.Lo[mt * 16 + l15][kb];
      acc[mt] = __builtin_amdgcn_mfma_f32_16x16x32_bf16(ah, bHi, acc[mt], 0, 0, 0);
      acc[mt] = __builtin_amdgcn_mfma_f32_16x16x32_bf16(ah, bLo, acc[mt], 0, 0, 0);
      acc[mt] = __builtin_amdgcn_mfma_f32_16x16x32_bf16(al, bHi, acc[mt], 0, 0, 0);
    }
  }
  float b1v, w2v, b2v;
  if (is_mask) {
    b1v = n < 54 ? mb1[n] : 0.f;
    w2v = n < 54 ? mw2[n] : 0.f;
    b2v = mb2[0];
  } else {
    b1v = ab1[n]; w2v = aw2[n]; b2v = ab2[0];
  }
  __syncthreads();  // Hi/Lo reads done -> red overlays
#pragma unroll
  for (int mt = 0; mt < 2; ++mt)
#pragma unroll
    for (int r2 = 0; r2 < 4; ++r2)
      sm.red[n][mt * 16 + q * 4 + r2] = fmaxf(acc[mt][r2] + b1v, 0.f) * w2v;
  __syncthreads();
  if (tid < 32) {
    float s = 0.f;
#pragma unroll
    for (int nn = 0; nn < 64; ++nn) s += sm.red[nn][tid];
    const float z = s + b2v;
    if (!is_mask) {
      evec[m0 + tid] = z;
    } else {
      const float thr = 3.f / (1.f + expf(-z));
#pragma unroll
      for (int li = 0; li < 3; ++li) {
        const float dd = (float)li - thr;
        maskL[li * N_NODES + m0 + tid] = expf(-dd * dd);
      }
    }
  }
}

// ---------------- sparse softmax aggregation: wave per node, register shuffle broadcast ----------------
__global__ __launch_bounds__(256) void agg4(const __hip_bfloat16* __restrict__ hb,
                                            const float* __restrict__ e,
                                            const int* __restrict__ col_idx,
                                            const int* __restrict__ deg,
                                            __hip_bfloat16* __restrict__ hagg) {
  const int w = threadIdx.x >> 6, lane = threadIdx.x & 63;
  const int node = blockIdx.x * 4 + w;
  const int d = deg[node];
  int c0 = 0, c1 = 0;
  float e0 = -3.0e38f, e1 = -3.0e38f;
  if (lane < d) { c0 = col_idx[(size_t)node * MAXD + lane]; e0 = e[c0]; }
  if (lane + 64 < d) { c1 = col_idx[(size_t)node * MAXD + lane + 64]; e1 = e[c1]; }
  float mx = fmaxf(e0, e1);
#pragma unroll
  for (int off = 32; off; off >>= 1) mx = fmaxf(mx, __shfl_xor(mx, off));
  const float p0 = lane < d ? expf(e0 - mx) : 0.f;
  const float p1 = lane + 64 < d ? expf(e1 - mx) : 0.f;
  float s = p0 + p1;
#pragma unroll
  for (int off = 32; off; off >>= 1) s += __shfl_xor(s, off);
  const float scale = (float)d / s;
  const float wv0 = p0 * scale, wv1 = p1 * scale;
  float4 a = {0.f, 0.f, 0.f, 0.f};
  const int d64 = d < 64 ? d : 64;
  int j = 0;
  for (; j + 2 <= d64; j += 2) {
    const int cc0 = __shfl(c0, j), cc1 = __shfl(c0, j + 1);
    const float w0 = __shfl(wv0, j), w1 = __shfl(wv0, j + 1);
    const ushort4 u0 = *(const ushort4*)(hb + (size_t)cc0 * 256 + lane * 4);
    const ushort4 u1 = *(const ushort4*)(hb + (size_t)cc1 * 256 + lane * 4);
    a.x += w0 * bfu(u0.x) + w1 * bfu(u1.x);
    a.y += w0 * bfu(u0.y) + w1 * bfu(u1.y);
    a.z += w0 * bfu(u0.z) + w1 * bfu(u1.z);
    a.w += w0 * bfu(u0.w) + w1 * bfu(u1.w);
  }
  if (j < d64) {
    const int cc0 = __shfl(c0, j);
    const float w0 = __shfl(wv0, j);
    const ushort4 u0 = *(const ushort4*)(hb + (size_t)cc0 * 256 + lane * 4);
    a.x += w0 * bfu(u0.x); a.y += w0 * bfu(u0.y);
    a.z += w0 * bfu(u0.z); a.w += w0 * bfu(u0.w);
  }
  for (j = 64; j < d; ++j) {  // cold path: d > 64 (essentially never)
    const int cc = __shfl(c1, j - 64);
    const float wv = __shfl(wv1, j - 64);
    const ushort4 u0 = *(const ushort4*)(hb + (size_t)cc * 256 + lane * 4);
    a.x += wv * bfu(u0.x); a.y += wv * bfu(u0.y);
    a.z += wv * bfu(u0.z); a.w += wv * bfu(u0.w);
  }
  union { __hip_bfloat16 h[4]; short4 s4; } pk;
  pk.h[0] = __float2bfloat16(a.x); pk.h[1] = __float2bfloat16(a.y);
  pk.h[2] = __float2bfloat16(a.z); pk.h[3] = __float2bfloat16(a.w);
  *(short4*)(hagg + (size_t)node * 256 + lane * 4) = pk.s4;
}

// ---------------- 64x64 MFMA tile accumulate (proven) ----------------
__device__ __forceinline__ void gemm_acc(char* AsB, char* WsB,
                                         const __hip_bfloat16* __restrict__ A,
                                         const __hip_bfloat16* __restrict__ Bt,
                                         int K, int m0, int n0, floatx4* acc) {
  const int tid = threadIdx.x, w = tid >> 6, lane = tid & 63;
  const int q = lane >> 4, l15 = lane & 15;
  const int nKT = K >> 6;
  for (int kt = 0; kt < nKT; ++kt) {
    const int kbase = kt * 64;
#pragma unroll
    for (int r = 0; r < 2; ++r) {
      const int s = w * 128 + r * 64 + lane;
      const int m = s >> 3;
      const int gch = (s & 7) ^ (m & 7);
      async16(AsB + (size_t)(w * 128 + r * 64) * 16,
              (const void*)(A + (size_t)(m0 + m) * K + kbase + gch * 8));
      async16(WsB + (size_t)(w * 128 + r * 64) * 16,
              (const void*)(Bt + (size_t)(n0 + m) * K + kbase + gch * 8));
    }
    __syncthreads();
#pragma unroll
    for (int kk = 0; kk < 2; ++kk) {
      const int gq = kk * 4 + q;
      const int nsl = w * 16 + l15;
      bf16x8 b = *(const bf16x8*)(WsB + (size_t)(nsl * 8 + (gq ^ (nsl & 7))) * 16);
#pragma unroll
      for (int mt = 0; mt < 4; ++mt) {
        const int msl = mt * 16 + l15;
        bf16x8 a = *(const bf16x8*)(AsB + (size_t)(msl * 8 + (gq ^ (msl & 7))) * 16);
        acc[mt] = __builtin_amdgcn_mfma_f32_16x16x32_bf16(a, b, acc[mt], 0, 0, 0);
      }
    }
    __syncthreads();
  }
}

// ---------------- bf16 MFMA GEMM: C = A @ Wt^T + bias; optional stats ----------------
template <bool OUT_BF16, bool RELU, bool STATS>
__global__ __launch_bounds__(256) void gemm_bf16(const __hip_bfloat16* __restrict__ A,
                                                 const __hip_bfloat16* __restrict__ Wt,
                                                 const float* __restrict__ bias,
                                                 void* __restrict__ Cout, int K, int ldc,
                                                 float* __restrict__ stats) {
  __shared__ __align__(16) char As[8192];
  __shared__ __align__(16) char Ws[8192];
  const int tid = threadIdx.x;
  const int w = tid >> 6;
  const int lane = tid & 63;
  const int m0 = blockIdx.x * 64;
  const int n0 = blockIdx.y * 64;
  const int q = lane >> 4, l15 = lane & 15;
  floatx4 acc[4] = {};
  gemm_acc(As, Ws, A, Wt, K, m0, n0, acc);
  const int n = n0 + w * 16 + l15;
  const float bv = bias[n];
  float s = 0.f, s2 = 0.f;
#pragma unroll
  for (int mt = 0; mt < 4; ++mt) {
#pragma unroll
    for (int r2 = 0; r2 < 4; ++r2) {
      const int m = m0 + mt * 16 + q * 4 + r2;
      float v = acc[mt][r2] + bv;
      if (RELU) v = fmaxf(v, 0.f);
      if (STATS) { s += v; s2 += v * v; }
      if (OUT_BF16)
        ((__hip_bfloat16*)Cout)[(size_t)m * ldc + n] = __float2bfloat16(v);
      else
        ((float*)Cout)[(size_t)m * ldc + n] = v;
    }
  }
  if (STATS) {
    s += __shfl_xor(s, 16); s += __shfl_xor(s, 32);
    s2 += __shfl_xor(s2, 16); s2 += __shfl_xor(s2, 32);
    if (q == 0) {
      atomicAdd(&stats[n], s);
      atomicAdd(&stats[256 + n], s2);
    }
  }
}

// ---------------- fused BN + e-MLP: BN(h2)->hbHi/feat + att MLP -> evec ----------------
// 256 blocks x 32 nodes (proven shape).
__global__ __launch_bounds__(256) void bn_emlp(
    const float* __restrict__ h2, const float* __restrict__ stats,
    const float* __restrict__ gamma, const float* __restrict__ beta,
    const float* __restrict__ maskl,
    const __hip_bfloat16* __restrict__ aHi, const __hip_bfloat16* __restrict__ aLo,
    const float* __restrict__ ab1, const float* __restrict__ aw2, const float* __restrict__ ab2,
    __hip_bfloat16* __restrict__ hbHi, __hip_bfloat16* __restrict__ feat, int l,
    float* __restrict__ evec) {
  __shared__ union {
    struct {
      __hip_bfloat16 Hi[32][264];
      __hip_bfloat16 Lo[32][264];
      float sc[256];
      float sh[256];
    } s;
    float red[64][36];
  } sm;
  const int tid = threadIdx.x, w = tid >> 6, lane = tid & 63;
  const int q = lane >> 4, l15 = lane & 15;
  const int m0 = blockIdx.x * 32;
  {
    const float inv_n = 1.f / 8192.f;
    const float mean = stats[tid] * inv_n;
    const float sc = rsqrtf(stats[256 + tid] * inv_n - mean * mean + 1e-5f) * gamma[tid];
    sm.s.sc[tid] = sc;
    sm.s.sh[tid] = beta[tid] - mean * sc;
  }
  __syncthreads();
  {
    const int row = tid >> 3, seg = tid & 7;
    const int node = m0 + row;
    const float fm = maskl[node];
#pragma unroll
    for (int it = 0; it < 4; ++it) {
      const int c = it * 64 + seg * 8;  // coalesced across seg
      const float4 vA = *(const float4*)(h2 + (size_t)node * 256 + c);
      const float4 vB = *(const float4*)(h2 + (size_t)node * 256 + c + 4);
      const float4 scA = *(const float4*)&sm.s.sc[c];
      const float4 scB = *(const float4*)&sm.s.sc[c + 4];
      const float4 shA = *(const float4*)&sm.s.sh[c];
      const float4 shB = *(const float4*)&sm.s.sh[c + 4];
      float o[8];
      o[0] = fmaxf(vA.x * scA.x + shA.x, 0.f);
      o[1] = fmaxf(vA.y * scA.y + shA.y, 0.f);
      o[2] = fmaxf(vA.z * scA.z + shA.z, 0.f);
      o[3] = fmaxf(vA.w * scA.w + shA.w, 0.f);
      o[4] = fmaxf(vB.x * scB.x + shB.x, 0.f);
      o[5] = fmaxf(vB.y * scB.y + shB.y, 0.f);
      o[6] = fmaxf(vB.z * scB.z + shB.z, 0.f);
      o[7] = fmaxf(vB.w * scB.w + shB.w, 0.f);
      union { __hip_bfloat16 h[8]; uint4 u; } ph, plo, pf;
#pragma unroll
      for (int i = 0; i < 8; ++i) {
        ph.h[i] = __float2bfloat16(o[i]);
        plo.h[i] = __float2bfloat16(o[i] - __bfloat162float(ph.h[i]));
        pf.h[i] = __float2bfloat16(o[i] * fm);
      }
      *(uint4*)&sm.s.Hi[row][c] = ph.u;
      *(uint4*)&sm.s.Lo[row][c] = plo.u;
      *(uint4*)(hbHi + (size_t)node * 256 + c) = ph.u;
      *(uint4*)(feat + (size_t)node * 768 + l * 256 + c) = pf.u;
    }
  }
  __syncthreads();
  const int n = w * 16 + l15;
  floatx4 acc[2] = {};
  for (int kc = 0; kc < 8; ++kc) {
    const int kb = kc * 32 + q * 8;
    const bf16x8 bHi = *(const bf16x8*)(aHi + (size_t)n * 256 + kb);
    const bf16x8 bLo = *(const bf16x8*)(aLo + (size_t)n * 256 + kb);
#pragma unroll
    for (int mt = 0; mt < 2; ++mt) {
      const bf16x8 ah = *(const bf16x8*)&sm.s.Hi[mt * 16 + l15][kb];
      const bf16x8 al = *(const bf16x8*)&sm.s.Lo[mt * 16 + l15][kb];
      acc[mt] = __builtin_amdgcn_mfma_f32_16x16x32_bf16(ah, bHi, acc[mt], 0, 0, 0);
      acc[mt] = __builtin_amdgcn_mfma_f32_16x16x32_bf16(ah, bLo, acc[mt], 0, 0, 0);
      acc[mt] = __builtin_amdgcn_mfma_f32_16x16x32_bf16(al, bHi, acc[mt], 0, 0, 0);
    }
  }
  const float b1v = ab1[n], w2v = aw2[n], b2v = ab2[0];
  __syncthreads();  // Hi/Lo reads done -> red overlays
#pragma unroll
  for (int mt = 0; mt < 2; ++mt)
#pragma unroll
    for (int r2 = 0; r2 < 4; ++r2)
      sm.red[n][mt * 16 + q * 4 + r2] = fmaxf(acc[mt][r2] + b1v, 0.f) * w2v;
  __syncthreads();
  if (tid < 32) {
    float s = 0.f;
#pragma unroll
    for (int nn = 0; nn < 64; ++nn) s += sm.red[nn][tid];
    evec[m0 + tid] = s + b2v;
  }
}

// ---------------- Y3: BN(l2) + feat-l2 in LDS + pred GEMM fused ----------------
__global__ __launch_bounds__(256) void layer_y3(const float* __restrict__ h2,
                                                const float* __restrict__ stats,
                                                const float* __restrict__ gamma,
                                                const float* __restrict__ beta,
                                                const float* __restrict__ maskl,
                                                const __hip_bfloat16* __restrict__ feat,
                                                const __hip_bfloat16* __restrict__ predWt,
                                                const float* __restrict__ pred_b,
                                                float* __restrict__ out) {
  __shared__ __hip_bfloat16 F[16][776];
  const int tid = threadIdx.x, w = tid >> 6, lane = tid & 63;
  const int q = lane >> 4, l15 = lane & 15;
  const int m0 = blockIdx.x * 16;
  const float inv_n = 1.f / 8192.f;
#pragma unroll
  for (int t = 0; t < 4; ++t) {  // feat l0/l1 -> cols 0..511
    const int idx = t * 256 + tid;
    const int row = idx >> 6, ch = idx & 63;
    const uint4 u = *(const uint4*)(feat + (size_t)(m0 + row) * 768 + ch * 8);
    *(uint4*)&F[row][ch * 8] = u;
  }
  {  // BN l2 -> cols 512..767
    const int i = w * 4 + q;
    const int node = m0 + i;
    const float fm = maskl[node];
#pragma unroll
    for (int cc = 0; cc < 4; ++cc) {
      const int c = l15 * 16 + cc * 4;
      const float4 sA = *(const float4*)&stats[c];
      const float4 sB = *(const float4*)&stats[256 + c];
      const float4 g4 = *(const float4*)&gamma[c];
      const float4 b4 = *(const float4*)&beta[c];
      const float4 v = *(const float4*)&h2[(size_t)node * 256 + c];
      float o[4];
      {
        float mn = sA.x * inv_n; o[0] = fmaxf((v.x - mn) * rsqrtf(sB.x * inv_n - mn * mn + 1e-5f) * g4.x + b4.x, 0.f);
        mn = sA.y * inv_n; o[1] = fmaxf((v.y - mn) * rsqrtf(sB.y * inv_n - mn * mn + 1e-5f) * g4.y + b4.y, 0.f);
        mn = sA.z * inv_n; o[2] = fmaxf((v.z - mn) * rsqrtf(sB.z * inv_n - mn * mn + 1e-5f) * g4.z + b4.z, 0.f);
        mn = sA.w * inv_n; o[3] = fmaxf((v.w - mn) * rsqrtf(sB.w * inv_n - mn * mn + 1e-5f) * g4.w + b4.w, 0.f);
      }
      union { __hip_bfloat16 h[4]; short4 s4; } pf;
#pragma unroll
      for (int k = 0; k < 4; ++k) pf.h[k] = __float2bfloat16(o[k] * fm);
      *(short4*)&F[i][512 + c] = pf.s4;
    }
  }
  __syncthreads();
  const int n = w * 16 + l15;
  floatx4 acc = {0.f, 0.f, 0.f, 0.f};
  for (int kc = 0; kc < 24; ++kc) {
    const int kb = kc * 32 + q * 8;
    const bf16x8 a = *(const bf16x8*)&F[l15][kb];
    const bf16x8 b = *(const bf16x8*)(predWt + (size_t)n * 768 + kb);
    acc = __builtin_amdgcn_mfma_f32_16x16x32_bf16(a, b, acc, 0, 0, 0);
  }
  const float bv = pred_b[n];
#pragma unroll
  for (int r2 = 0; r2 < 4; ++r2)
    out[(size_t)(m0 + q * 4 + r2) * 64 + n] = acc[r2] + bv;
}

extern "C" void kernel_launch(void* const* d_in, const int* in_sizes, int n_in,
                              void* d_out, int out_size, void* d_ws, size_t ws_size,
                              hipStream_t stream) {
  (void)in_sizes; (void)n_in; (void)out_size; (void)ws_size;
  const float* graph   = (const float*)d_in[0];
  const float* x       = (const float*)d_in[1];
  const float* att_W1  = (const float*)d_in[2];
  const float* att_b1  = (const float*)d_in[3];
  const float* att_W2  = (const float*)d_in[4];
  const float* att_b2  = (const float*)d_in[5];
  const float* mlp_W1  = (const float*)d_in[6];
  const float* mlp_b1  = (const float*)d_in[7];
  const float* mlp_W2  = (const float*)d_in[8];
  const float* mlp_b2  = (const float*)d_in[9];
  const float* bn_g    = (const float*)d_in[10];
  const float* bn_b    = (const float*)d_in[11];
  const float* mask_W1 = (const float*)d_in[12];
  const float* mask_b1 = (const float*)d_in[13];
  const float* mask_W2 = (const float*)d_in[14];
  const float* mask_b2 = (const float*)d_in[15];
  const float* pred_W  = (const float*)d_in[16];
  const float* pred_b  = (const float*)d_in[17];
  float* out = (float*)d_out;

  char* ws = (char*)d_ws;
  size_t off = 0;
  auto carve = [&](size_t bytes) -> char* {
    char* p = ws + off;
    off += (bytes + 255) & ~(size_t)255;
    return p;
  };
  __hip_bfloat16* Wt1    = (__hip_bfloat16*)carve((size_t)3 * 65536 * 2);
  __hip_bfloat16* Wt2    = (__hip_bfloat16*)carve((size_t)3 * 65536 * 2);
  __hip_bfloat16* attHi  = (__hip_bfloat16*)carve((size_t)3 * 16384 * 2);
  __hip_bfloat16* attLo  = (__hip_bfloat16*)carve((size_t)3 * 16384 * 2);
  __hip_bfloat16* maskHi = (__hip_bfloat16*)carve((size_t)64 * 256 * 2);
  __hip_bfloat16* maskLo = (__hip_bfloat16*)carve((size_t)64 * 256 * 2);
  __hip_bfloat16* predWt = (__hip_bfloat16*)carve((size_t)64 * 768 * 2);
  int*   col_idx = (int*)carve((size_t)N_NODES * MAXD * 4);
  int*   deg     = (int*)carve((size_t)N_NODES * 4);
  float* evec    = (float*)carve((size_t)N_NODES * 4);
  float* maskL   = (float*)carve((size_t)3 * N_NODES * 4);
  float* stats   = (float*)carve((size_t)3 * 512 * 4);
  float* h2      = (float*)carve((size_t)N_NODES * 256 * 4);
  __hip_bfloat16* hbHi = (__hip_bfloat16*)carve((size_t)N_NODES * 256 * 2);
  __hip_bfloat16* hagg = (__hip_bfloat16*)carve((size_t)N_NODES * 256 * 2);
  __hip_bfloat16* H1   = (__hip_bfloat16*)carve((size_t)N_NODES * 256 * 2);
  __hip_bfloat16* feat = (__hip_bfloat16*)carve((size_t)N_NODES * 768 * 2);

  prep_w<<<482, 256, 0, stream>>>(mlp_W1, mlp_W2, att_W1, pred_W, mask_W1,
                                  Wt1, Wt2, attHi, attLo, predWt, maskHi, maskLo, stats);
  scan_emlp<<<9216, 256, 0, stream>>>(x, graph, attHi, attLo, att_b1, att_W2, att_b2,
                                      maskHi, maskLo, mask_b1, mask_W2, mask_b2,
                                      hbHi, evec, maskL, col_idx, deg);
  for (int l = 0; l < 3; ++l) {
    agg4<<<N_NODES / 4, 256, 0, stream>>>(hbHi, evec, col_idx, deg, hagg);
    gemm_bf16<true, true, false><<<dim3(128, 4), 256, 0, stream>>>(
        hagg, Wt1 + (size_t)l * 65536, mlp_b1 + l * 256, H1, 256, 256, nullptr);
    gemm_bf16<false, false, true><<<dim3(128, 4), 256, 0, stream>>>(
        H1, Wt2 + (size_t)l * 65536, mlp_b2 + l * 256, h2, 256, 256, stats + l * 512);
    if (l < 2) {
      bn_emlp<<<256, 256, 0, stream>>>(h2, stats + l * 512, bn_g + l * 256, bn_b + l * 256,
                                       maskL + l * N_NODES,
                                       attHi + (size_t)(l + 1) * 16384,
                                       attLo + (size_t)(l + 1) * 16384,
                                       att_b1 + (l + 1) * 64, att_W2 + (l + 1) * 64,
                                       att_b2 + (l + 1),
                                       hbHi, feat, l, evec);
    } else {
      layer_y3<<<512, 256, 0, stream>>>(h2, stats + l * 512, bn_g + l * 256, bn_b + l * 256,
                                        maskL + l * N_NODES, feat, predWt, pred_b, out);
    }
  }
}

// Round 6
// 491.235 us; speedup vs baseline: 1.0299x; 1.0299x over previous
//
#include <hip/hip_runtime.h>
#include <hip/hip_bf16.h>

#define N_NODES 8192
#define MAXD 128

typedef __attribute__((ext_vector_type(8))) __bf16 bf16x8;
typedef __attribute__((ext_vector_type(4))) float floatx4;
typedef float __attribute__((ext_vector_type(4))) f32x4;

__device__ __forceinline__ void async16(void* lds, const void* g) {
  __builtin_amdgcn_global_load_lds((const __attribute__((address_space(1))) void*)g,
                                   (__attribute__((address_space(3))) void*)lds, 16, 0, 0);
}

__device__ __forceinline__ float bfu(unsigned short u) {
  union { unsigned int i; float f; } c; c.i = (unsigned int)u << 16; return c.f;
}

// ---------------- prep (transposes, hi/lo splits, x->bf16, stats zero) + CSR build ----------------
__global__ __launch_bounds__(256) void prep_csr(const float* __restrict__ mlp_W1,
                                                const float* __restrict__ mlp_W2,
                                                const float* __restrict__ att_W1,
                                                const float* __restrict__ pred_W,
                                                const float* __restrict__ mask_W1,
                                                const float* __restrict__ x,
                                                const float* __restrict__ graph,
                                                __hip_bfloat16* __restrict__ Wt1,
                                                __hip_bfloat16* __restrict__ Wt2,
                                                __hip_bfloat16* __restrict__ attHi,
                                                __hip_bfloat16* __restrict__ attLo,
                                                __hip_bfloat16* __restrict__ predWt,
                                                __hip_bfloat16* __restrict__ maskHi,
                                                __hip_bfloat16* __restrict__ maskLo,
                                                __hip_bfloat16* __restrict__ hbHi,
                                                float* __restrict__ stats,
                                                int* __restrict__ col_idx,
                                                int* __restrict__ deg) {
  __shared__ union { float tile[32][33]; int cnt; } sm;
  const int blk = blockIdx.x, tid = threadIdx.x;
  if (blk >= 994) {  // CSR: block per row, 2048 loads in flight, nontemporal stream
    const int i = blk - 994;
    if (tid == 0) sm.cnt = 0;
    __syncthreads();
    const f32x4* row = (const f32x4*)(graph + (size_t)i * N_NODES);
#pragma unroll
    for (int it = 0; it < 8; ++it) {
      const int idx = it * 256 + tid;
      f32x4 v = __builtin_nontemporal_load(&row[idx]);
      if (v.x > 0.f) { int p = atomicAdd(&sm.cnt, 1); if (p < MAXD) col_idx[(size_t)i * MAXD + p] = idx * 4 + 0; }
      if (v.y > 0.f) { int p = atomicAdd(&sm.cnt, 1); if (p < MAXD) col_idx[(size_t)i * MAXD + p] = idx * 4 + 1; }
      if (v.z > 0.f) { int p = atomicAdd(&sm.cnt, 1); if (p < MAXD) col_idx[(size_t)i * MAXD + p] = idx * 4 + 2; }
      if (v.w > 0.f) { int p = atomicAdd(&sm.cnt, 1); if (p < MAXD) col_idx[(size_t)i * MAXD + p] = idx * 4 + 3; }
    }
    __syncthreads();
    if (tid == 0) deg[i] = sm.cnt < MAXD ? sm.cnt : MAXD;
    return;
  }
  if (blk < 480) {
    const int tx = tid & 31, ty = tid >> 5;
    const float* in; __hip_bfloat16* oh; __hip_bfloat16* ol = nullptr;
    int K, N, kt, nt;
    if (blk < 384) {
      const int z = blk / 64, rem = blk % 64; kt = rem / 8; nt = rem % 8; K = 256; N = 256;
      in = z < 3 ? mlp_W1 + (size_t)z * 65536 : mlp_W2 + (size_t)(z - 3) * 65536;
      oh = z < 3 ? Wt1 + (size_t)z * 65536 : Wt2 + (size_t)(z - 3) * 65536;
    } else if (blk < 432) {
      const int i = blk - 384, z = i / 16, rem = i % 16; kt = rem / 2; nt = rem & 1;
      K = 256; N = 64;
      in = att_W1 + (size_t)z * 16384; oh = attHi + (size_t)z * 16384;
      ol = attLo + (size_t)z * 16384;
    } else {
      const int i = blk - 432; kt = i / 2; nt = i & 1; K = 768; N = 64;
      in = pred_W; oh = predWt;
    }
    const int k0 = kt * 32, n0 = nt * 32;
#pragma unroll
    for (int r = 0; r < 4; ++r)
      sm.tile[ty + r * 8][tx] = in[(size_t)(k0 + ty + r * 8) * N + n0 + tx];
    __syncthreads();
#pragma unroll
    for (int r = 0; r < 4; ++r) {
      const float v = sm.tile[tx][ty + r * 8];
      const __hip_bfloat16 hi = __float2bfloat16(v);
      oh[(size_t)(n0 + ty + r * 8) * K + k0 + tx] = hi;
      if (ol)
        ol[(size_t)(n0 + ty + r * 8) * K + k0 + tx] =
            __float2bfloat16(v - __bfloat162float(hi));
    }
  } else if (blk == 480) {
    for (int i = tid; i < 16384; i += 256) {
      const int n = i >> 8, k = i & 255;
      const float v = (n < 54) ? mask_W1[k * 54 + n] : 0.f;
      const __hip_bfloat16 hi = __float2bfloat16(v);
      maskHi[n * 256 + k] = hi;
      maskLo[n * 256 + k] = __float2bfloat16(v - __bfloat162float(hi));
    }
  } else if (blk == 481) {
    for (int i = tid; i < 1536; i += 256) stats[i] = 0.f;
  } else {
    const float4* xv = (const float4*)x;
    const int base = (blk - 482) * 1024;
#pragma unroll
    for (int it = 0; it < 4; ++it) {
      const int i = base + it * 256 + tid;
      const float4 v = xv[i];
      union { __hip_bfloat16 h[4]; short4 s4; } ph;
      ph.h[0] = __float2bfloat16(v.x); ph.h[1] = __float2bfloat16(v.y);
      ph.h[2] = __float2bfloat16(v.z); ph.h[3] = __float2bfloat16(v.w);
      ((short4*)hbHi)[i] = ph.s4;
    }
  }
}

// ---------------- e/mask MLP (first call on x): stage x hi/lo in LDS, W direct from L2 ----------------
__global__ __launch_bounds__(256) void emlp2_kernel(
    const float* __restrict__ x,
    const __hip_bfloat16* __restrict__ aHi, const __hip_bfloat16* __restrict__ aLo,
    const float* __restrict__ ab1, const float* __restrict__ aw2, const float* __restrict__ ab2,
    const __hip_bfloat16* __restrict__ mHi, const __hip_bfloat16* __restrict__ mLo,
    const float* __restrict__ mb1, const float* __restrict__ mw2, const float* __restrict__ mb2,
    float* __restrict__ evec, float* __restrict__ maskL) {
  __shared__ union {
    struct { __hip_bfloat16 Hi[64][264]; __hip_bfloat16 Lo[64][264]; } s;
    float red[64][65];
  } sm;
  const int tid = threadIdx.x, w = tid >> 6, lane = tid & 63;
  const int q = lane >> 4, l15 = lane & 15;
  const bool is_mask = blockIdx.x >= 128;
  const int m0 = (is_mask ? (int)blockIdx.x - 128 : (int)blockIdx.x) * 64;
  {
    const float4* xv = (const float4*)x;
#pragma unroll
    for (int t = 0; t < 16; ++t) {  // 64 rows x 64 float4
      const int i = t * 256 + tid;
      const int row = i >> 6, c4 = i & 63;
      const float4 v = xv[(size_t)(m0 + row) * 64 + c4];
      union { __hip_bfloat16 h[4]; short4 s4; } ph, pl;
      ph.h[0] = __float2bfloat16(v.x); ph.h[1] = __float2bfloat16(v.y);
      ph.h[2] = __float2bfloat16(v.z); ph.h[3] = __float2bfloat16(v.w);
      pl.h[0] = __float2bfloat16(v.x - __bfloat162float(ph.h[0]));
      pl.h[1] = __float2bfloat16(v.y - __bfloat162float(ph.h[1]));
      pl.h[2] = __float2bfloat16(v.z - __bfloat162float(ph.h[2]));
      pl.h[3] = __float2bfloat16(v.w - __bfloat162float(ph.h[3]));
      *(short4*)&sm.s.Hi[row][c4 * 4] = ph.s4;
      *(short4*)&sm.s.Lo[row][c4 * 4] = pl.s4;
    }
  }
  __syncthreads();
  const __hip_bfloat16* Whi = is_mask ? mHi : aHi;
  const __hip_bfloat16* Wlo = is_mask ? mLo : aLo;
  const int n = w * 16 + l15;
  floatx4 acc[4] = {};
  for (int kc = 0; kc < 8; ++kc) {
    const int kb = kc * 32 + q * 8;
    const bf16x8 bHi = *(const bf16x8*)(Whi + (size_t)n * 256 + kb);
    const bf16x8 bLo = *(const bf16x8*)(Wlo + (size_t)n * 256 + kb);
#pragma unroll
    for (int mt = 0; mt < 4; ++mt) {
      const bf16x8 ah = *(const bf16x8*)&sm.s.Hi[mt * 16 + l15][kb];
      const bf16x8 al = *(const bf16x8*)&sm.s.Lo[mt * 16 + l15][kb];
      acc[mt] = __builtin_amdgcn_mfma_f32_16x16x32_bf16(ah, bHi, acc[mt], 0, 0, 0);
      acc[mt] = __builtin_amdgcn_mfma_f32_16x16x32_bf16(ah, bLo, acc[mt], 0, 0, 0);
      acc[mt] = __builtin_amdgcn_mfma_f32_16x16x32_bf16(al, bHi, acc[mt], 0, 0, 0);
    }
  }
  float b1v, w2v, b2v;
  if (is_mask) {
    b1v = n < 54 ? mb1[n] : 0.f;
    w2v = n < 54 ? mw2[n] : 0.f;
    b2v = mb2[0];
  } else {
    b1v = ab1[n]; w2v = aw2[n]; b2v = ab2[0];
  }
  __syncthreads();  // strips -> red (union reuse)
#pragma unroll
  for (int mt = 0; mt < 4; ++mt)
#pragma unroll
    for (int r2 = 0; r2 < 4; ++r2)
      sm.red[n][mt * 16 + q * 4 + r2] = fmaxf(acc[mt][r2] + b1v, 0.f) * w2v;
  __syncthreads();
  if (tid < 64) {
    float s = 0.f;
#pragma unroll
    for (int nn = 0; nn < 64; ++nn) s += sm.red[nn][tid];
    const float z = s + b2v;
    if (!is_mask) {
      evec[m0 + tid] = z;
    } else {
      const float thr = 3.f / (1.f + expf(-z));
#pragma unroll
      for (int li = 0; li < 3; ++li) {
        const float dd = (float)li - thr;
        maskL[li * N_NODES + m0 + tid] = expf(-dd * dd);
      }
    }
  }
}

// ---------------- sparse softmax aggregation: wave per node, register shuffle broadcast ----------------
__global__ __launch_bounds__(256) void agg4(const __hip_bfloat16* __restrict__ hb,
                                            const float* __restrict__ e,
                                            const int* __restrict__ col_idx,
                                            const int* __restrict__ deg,
                                            __hip_bfloat16* __restrict__ hagg) {
  const int w = threadIdx.x >> 6, lane = threadIdx.x & 63;
  const int node = blockIdx.x * 4 + w;
  const int d = deg[node];
  int c0 = 0, c1 = 0;
  float e0 = -3.0e38f, e1 = -3.0e38f;
  if (lane < d) { c0 = col_idx[(size_t)node * MAXD + lane]; e0 = e[c0]; }
  if (lane + 64 < d) { c1 = col_idx[(size_t)node * MAXD + lane + 64]; e1 = e[c1]; }
  float mx = fmaxf(e0, e1);
#pragma unroll
  for (int off = 32; off; off >>= 1) mx = fmaxf(mx, __shfl_xor(mx, off));
  const float p0 = lane < d ? expf(e0 - mx) : 0.f;
  const float p1 = lane + 64 < d ? expf(e1 - mx) : 0.f;
  float s = p0 + p1;
#pragma unroll
  for (int off = 32; off; off >>= 1) s += __shfl_xor(s, off);
  const float scale = (float)d / s;
  const float wv0 = p0 * scale, wv1 = p1 * scale;
  float4 a = {0.f, 0.f, 0.f, 0.f};
  const int d64 = d < 64 ? d : 64;
  int j = 0;
  for (; j + 2 <= d64; j += 2) {
    const int cc0 = __shfl(c0, j), cc1 = __shfl(c0, j + 1);
    const float w0 = __shfl(wv0, j), w1 = __shfl(wv0, j + 1);
    const ushort4 u0 = *(const ushort4*)(hb + (size_t)cc0 * 256 + lane * 4);
    const ushort4 u1 = *(const ushort4*)(hb + (size_t)cc1 * 256 + lane * 4);
    a.x += w0 * bfu(u0.x) + w1 * bfu(u1.x);
    a.y += w0 * bfu(u0.y) + w1 * bfu(u1.y);
    a.z += w0 * bfu(u0.z) + w1 * bfu(u1.z);
    a.w += w0 * bfu(u0.w) + w1 * bfu(u1.w);
  }
  if (j < d64) {
    const int cc0 = __shfl(c0, j);
    const float w0 = __shfl(wv0, j);
    const ushort4 u0 = *(const ushort4*)(hb + (size_t)cc0 * 256 + lane * 4);
    a.x += w0 * bfu(u0.x); a.y += w0 * bfu(u0.y);
    a.z += w0 * bfu(u0.z); a.w += w0 * bfu(u0.w);
  }
  for (j = 64; j < d; ++j) {  // cold path: d > 64 (essentially never)
    const int cc = __shfl(c1, j - 64);
    const float wv = __shfl(wv1, j - 64);
    const ushort4 u0 = *(const ushort4*)(hb + (size_t)cc * 256 + lane * 4);
    a.x += wv * bfu(u0.x); a.y += wv * bfu(u0.y);
    a.z += wv * bfu(u0.z); a.w += wv * bfu(u0.w);
  }
  union { __hip_bfloat16 h[4]; short4 s4; } pk;
  pk.h[0] = __float2bfloat16(a.x); pk.h[1] = __float2bfloat16(a.y);
  pk.h[2] = __float2bfloat16(a.z); pk.h[3] = __float2bfloat16(a.w);
  *(short4*)(hagg + (size_t)node * 256 + lane * 4) = pk.s4;
}

// ---------------- 64x64 MFMA tile accumulate (proven) ----------------
__device__ __forceinline__ void gemm_acc(char* AsB, char* WsB,
                                         const __hip_bfloat16* __restrict__ A,
                                         const __hip_bfloat16* __restrict__ Bt,
                                         int K, int m0, int n0, floatx4* acc) {
  const int tid = threadIdx.x, w = tid >> 6, lane = tid & 63;
  const int q = lane >> 4, l15 = lane & 15;
  const int nKT = K >> 6;
  for (int kt = 0; kt < nKT; ++kt) {
    const int kbase = kt * 64;
#pragma unroll
    for (int r = 0; r < 2; ++r) {
      const int s = w * 128 + r * 64 + lane;
      const int m = s >> 3;
      const int gch = (s & 7) ^ (m & 7);
      async16(AsB + (size_t)(w * 128 + r * 64) * 16,
              (const void*)(A + (size_t)(m0 + m) * K + kbase + gch * 8));
      async16(WsB + (size_t)(w * 128 + r * 64) * 16,
              (const void*)(Bt + (size_t)(n0 + m) * K + kbase + gch * 8));
    }
    __syncthreads();
#pragma unroll
    for (int kk = 0; kk < 2; ++kk) {
      const int gq = kk * 4 + q;
      const int nsl = w * 16 + l15;
      bf16x8 b = *(const bf16x8*)(WsB + (size_t)(nsl * 8 + (gq ^ (nsl & 7))) * 16);
#pragma unroll
      for (int mt = 0; mt < 4; ++mt) {
        const int msl = mt * 16 + l15;
        bf16x8 a = *(const bf16x8*)(AsB + (size_t)(msl * 8 + (gq ^ (msl & 7))) * 16);
        acc[mt] = __builtin_amdgcn_mfma_f32_16x16x32_bf16(a, b, acc[mt], 0, 0, 0);
      }
    }
    __syncthreads();
  }
}

// ---------------- bf16 MFMA GEMM: C = A @ Wt^T + bias; optional stats ----------------
template <bool OUT_BF16, bool RELU, bool STATS>
__global__ __launch_bounds__(256) void gemm_bf16(const __hip_bfloat16* __restrict__ A,
                                                 const __hip_bfloat16* __restrict__ Wt,
                                                 const float* __restrict__ bias,
                                                 void* __restrict__ Cout, int K, int ldc,
                                                 float* __restrict__ stats) {
  __shared__ __align__(16) char As[8192];
  __shared__ __align__(16) char Ws[8192];
  const int tid = threadIdx.x;
  const int w = tid >> 6;
  const int lane = tid & 63;
  const int m0 = blockIdx.x * 64;
  const int n0 = blockIdx.y * 64;
  const int q = lane >> 4, l15 = lane & 15;
  floatx4 acc[4] = {};
  gemm_acc(As, Ws, A, Wt, K, m0, n0, acc);
  const int n = n0 + w * 16 + l15;
  const float bv = bias[n];
  float s = 0.f, s2 = 0.f;
#pragma unroll
  for (int mt = 0; mt < 4; ++mt) {
#pragma unroll
    for (int r2 = 0; r2 < 4; ++r2) {
      const int m = m0 + mt * 16 + q * 4 + r2;
      float v = acc[mt][r2] + bv;
      if (RELU) v = fmaxf(v, 0.f);
      if (STATS) { s += v; s2 += v * v; }
      if (OUT_BF16)
        ((__hip_bfloat16*)Cout)[(size_t)m * ldc + n] = __float2bfloat16(v);
      else
        ((float*)Cout)[(size_t)m * ldc + n] = v;
    }
  }
  if (STATS) {
    s += __shfl_xor(s, 16); s += __shfl_xor(s, 32);
    s2 += __shfl_xor(s2, 16); s2 += __shfl_xor(s2, 32);
    if (q == 0) {
      atomicAdd(&stats[n], s);
      atomicAdd(&stats[256 + n], s2);
    }
  }
}

// ---------------- fused BN + e-MLP: BN(h2)->hbHi/feat + att MLP -> evec ----------------
// 256 blocks x 32 nodes (proven shape).
__global__ __launch_bounds__(256) void bn_emlp(
    const float* __restrict__ h2, const float* __restrict__ stats,
    const float* __restrict__ gamma, const float* __restrict__ beta,
    const float* __restrict__ maskl,
    const __hip_bfloat16* __restrict__ aHi, const __hip_bfloat16* __restrict__ aLo,
    const float* __restrict__ ab1, const float* __restrict__ aw2, const float* __restrict__ ab2,
    __hip_bfloat16* __restrict__ hbHi, __hip_bfloat16* __restrict__ feat, int l,
    float* __restrict__ evec) {
  __shared__ union {
    struct {
      __hip_bfloat16 Hi[32][264];
      __hip_bfloat16 Lo[32][264];
      float sc[256];
      float sh[256];
    } s;
    float red[64][36];
  } sm;
  const int tid = threadIdx.x, w = tid >> 6, lane = tid & 63;
  const int q = lane >> 4, l15 = lane & 15;
  const int m0 = blockIdx.x * 32;
  {
    const float inv_n = 1.f / 8192.f;
    const float mean = stats[tid] * inv_n;
    const float sc = rsqrtf(stats[256 + tid] * inv_n - mean * mean + 1e-5f) * gamma[tid];
    sm.s.sc[tid] = sc;
    sm.s.sh[tid] = beta[tid] - mean * sc;
  }
  __syncthreads();
  {
    const int row = tid >> 3, seg = tid & 7;
    const int node = m0 + row;
    const float fm = maskl[node];
#pragma unroll
    for (int it = 0; it < 4; ++it) {
      const int c = it * 64 + seg * 8;  // coalesced across seg
      const float4 vA = *(const float4*)(h2 + (size_t)node * 256 + c);
      const float4 vB = *(const float4*)(h2 + (size_t)node * 256 + c + 4);
      const float4 scA = *(const float4*)&sm.s.sc[c];
      const float4 scB = *(const float4*)&sm.s.sc[c + 4];
      const float4 shA = *(const float4*)&sm.s.sh[c];
      const float4 shB = *(const float4*)&sm.s.sh[c + 4];
      float o[8];
      o[0] = fmaxf(vA.x * scA.x + shA.x, 0.f);
      o[1] = fmaxf(vA.y * scA.y + shA.y, 0.f);
      o[2] = fmaxf(vA.z * scA.z + shA.z, 0.f);
      o[3] = fmaxf(vA.w * scA.w + shA.w, 0.f);
      o[4] = fmaxf(vB.x * scB.x + shB.x, 0.f);
      o[5] = fmaxf(vB.y * scB.y + shB.y, 0.f);
      o[6] = fmaxf(vB.z * scB.z + shB.z, 0.f);
      o[7] = fmaxf(vB.w * scB.w + shB.w, 0.f);
      union { __hip_bfloat16 h[8]; uint4 u; } ph, plo, pf;
#pragma unroll
      for (int i = 0; i < 8; ++i) {
        ph.h[i] = __float2bfloat16(o[i]);
        plo.h[i] = __float2bfloat16(o[i] - __bfloat162float(ph.h[i]));
        pf.h[i] = __float2bfloat16(o[i] * fm);
      }
      *(uint4*)&sm.s.Hi[row][c] = ph.u;
      *(uint4*)&sm.s.Lo[row][c] = plo.u;
      *(uint4*)(hbHi + (size_t)node * 256 + c) = ph.u;
      *(uint4*)(feat + (size_t)node * 768 + l * 256 + c) = pf.u;
    }
  }
  __syncthreads();
  const int n = w * 16 + l15;
  floatx4 acc[2] = {};
  for (int kc = 0; kc < 8; ++kc) {
    const int kb = kc * 32 + q * 8;
    const bf16x8 bHi = *(const bf16x8*)(aHi + (size_t)n * 256 + kb);
    const bf16x8 bLo = *(const bf16x8*)(aLo + (size_t)n * 256 + kb);
#pragma unroll
    for (int mt = 0; mt < 2; ++mt) {
      const bf16x8 ah = *(const bf16x8*)&sm.s.Hi[mt * 16 + l15][kb];
      const bf16x8 al = *(const bf16x8*)&sm.s.Lo[mt * 16 + l15][kb];
      acc[mt] = __builtin_amdgcn_mfma_f32_16x16x32_bf16(ah, bHi, acc[mt], 0, 0, 0);
      acc[mt] = __builtin_amdgcn_mfma_f32_16x16x32_bf16(ah, bLo, acc[mt], 0, 0, 0);
      acc[mt] = __builtin_amdgcn_mfma_f32_16x16x32_bf16(al, bHi, acc[mt], 0, 0, 0);
    }
  }
  const float b1v = ab1[n], w2v = aw2[n], b2v = ab2[0];
  __syncthreads();  // Hi/Lo reads done -> red overlays
#pragma unroll
  for (int mt = 0; mt < 2; ++mt)
#pragma unroll
    for (int r2 = 0; r2 < 4; ++r2)
      sm.red[n][mt * 16 + q * 4 + r2] = fmaxf(acc[mt][r2] + b1v, 0.f) * w2v;
  __syncthreads();
  if (tid < 32) {
    float s = 0.f;
#pragma unroll
    for (int nn = 0; nn < 64; ++nn) s += sm.red[nn][tid];
    evec[m0 + tid] = s + b2v;
  }
}

// ---------------- Y3: BN(l2) + feat-l2 in LDS + pred GEMM fused ----------------
__global__ __launch_bounds__(256) void layer_y3(const float* __restrict__ h2,
                                                const float* __restrict__ stats,
                                                const float* __restrict__ gamma,
                                                const float* __restrict__ beta,
                                                const float* __restrict__ maskl,
                                                const __hip_bfloat16* __restrict__ feat,
                                                const __hip_bfloat16* __restrict__ predWt,
                                                const float* __restrict__ pred_b,
                                                float* __restrict__ out) {
  __shared__ __hip_bfloat16 F[16][776];
  const int tid = threadIdx.x, w = tid >> 6, lane = tid & 63;
  const int q = lane >> 4, l15 = lane & 15;
  const int m0 = blockIdx.x * 16;
  const float inv_n = 1.f / 8192.f;
#pragma unroll
  for (int t = 0; t < 4; ++t) {  // feat l0/l1 -> cols 0..511
    const int idx = t * 256 + tid;
    const int row = idx >> 6, ch = idx & 63;
    const uint4 u = *(const uint4*)(feat + (size_t)(m0 + row) * 768 + ch * 8);
    *(uint4*)&F[row][ch * 8] = u;
  }
  {  // BN l2 -> cols 512..767
    const int i = w * 4 + q;
    const int node = m0 + i;
    const float fm = maskl[node];
#pragma unroll
    for (int cc = 0; cc < 4; ++cc) {
      const int c = l15 * 16 + cc * 4;
      const float4 sA = *(const float4*)&stats[c];
      const float4 sB = *(const float4*)&stats[256 + c];
      const float4 g4 = *(const float4*)&gamma[c];
      const float4 b4 = *(const float4*)&beta[c];
      const float4 v = *(const float4*)&h2[(size_t)node * 256 + c];
      float o[4];
      {
        float mn = sA.x * inv_n; o[0] = fmaxf((v.x - mn) * rsqrtf(sB.x * inv_n - mn * mn + 1e-5f) * g4.x + b4.x, 0.f);
        mn = sA.y * inv_n; o[1] = fmaxf((v.y - mn) * rsqrtf(sB.y * inv_n - mn * mn + 1e-5f) * g4.y + b4.y, 0.f);
        mn = sA.z * inv_n; o[2] = fmaxf((v.z - mn) * rsqrtf(sB.z * inv_n - mn * mn + 1e-5f) * g4.z + b4.z, 0.f);
        mn = sA.w * inv_n; o[3] = fmaxf((v.w - mn) * rsqrtf(sB.w * inv_n - mn * mn + 1e-5f) * g4.w + b4.w, 0.f);
      }
      union { __hip_bfloat16 h[4]; short4 s4; } pf;
#pragma unroll
      for (int k = 0; k < 4; ++k) pf.h[k] = __float2bfloat16(o[k] * fm);
      *(short4*)&F[i][512 + c] = pf.s4;
    }
  }
  __syncthreads();
  const int n = w * 16 + l15;
  floatx4 acc = {0.f, 0.f, 0.f, 0.f};
  for (int kc = 0; kc < 24; ++kc) {
    const int kb = kc * 32 + q * 8;
    const bf16x8 a = *(const bf16x8*)&F[l15][kb];
    const bf16x8 b = *(const bf16x8*)(predWt + (size_t)n * 768 + kb);
    acc = __builtin_amdgcn_mfma_f32_16x16x32_bf16(a, b, acc, 0, 0, 0);
  }
  const float bv = pred_b[n];
#pragma unroll
  for (int r2 = 0; r2 < 4; ++r2)
    out[(size_t)(m0 + q * 4 + r2) * 64 + n] = acc[r2] + bv;
}

extern "C" void kernel_launch(void* const* d_in, const int* in_sizes, int n_in,
                              void* d_out, int out_size, void* d_ws, size_t ws_size,
                              hipStream_t stream) {
  (void)in_sizes; (void)n_in; (void)out_size; (void)ws_size;
  const float* graph   = (const float*)d_in[0];
  const float* x       = (const float*)d_in[1];
  const float* att_W1  = (const float*)d_in[2];
  const float* att_b1  = (const float*)d_in[3];
  const float* att_W2  = (const float*)d_in[4];
  const float* att_b2  = (const float*)d_in[5];
  const float* mlp_W1  = (const float*)d_in[6];
  const float* mlp_b1  = (const float*)d_in[7];
  const float* mlp_W2  = (const float*)d_in[8];
  const float* mlp_b2  = (const float*)d_in[9];
  const float* bn_g    = (const float*)d_in[10];
  const float* bn_b    = (const float*)d_in[11];
  const float* mask_W1 = (const float*)d_in[12];
  const float* mask_b1 = (const float*)d_in[13];
  const float* mask_W2 = (const float*)d_in[14];
  const float* mask_b2 = (const float*)d_in[15];
  const float* pred_W  = (const float*)d_in[16];
  const float* pred_b  = (const float*)d_in[17];
  float* out = (float*)d_out;

  char* ws = (char*)d_ws;
  size_t off = 0;
  auto carve = [&](size_t bytes) -> char* {
    char* p = ws + off;
    off += (bytes + 255) & ~(size_t)255;
    return p;
  };
  __hip_bfloat16* Wt1    = (__hip_bfloat16*)carve((size_t)3 * 65536 * 2);
  __hip_bfloat16* Wt2    = (__hip_bfloat16*)carve((size_t)3 * 65536 * 2);
  __hip_bfloat16* attHi  = (__hip_bfloat16*)carve((size_t)3 * 16384 * 2);
  __hip_bfloat16* attLo  = (__hip_bfloat16*)carve((size_t)3 * 16384 * 2);
  __hip_bfloat16* maskHi = (__hip_bfloat16*)carve((size_t)64 * 256 * 2);
  __hip_bfloat16* maskLo = (__hip_bfloat16*)carve((size_t)64 * 256 * 2);
  __hip_bfloat16* predWt = (__hip_bfloat16*)carve((size_t)64 * 768 * 2);
  int*   col_idx = (int*)carve((size_t)N_NODES * MAXD * 4);
  int*   deg     = (int*)carve((size_t)N_NODES * 4);
  float* evec    = (float*)carve((size_t)N_NODES * 4);
  float* maskL   = (float*)carve((size_t)3 * N_NODES * 4);
  float* stats   = (float*)carve((size_t)3 * 512 * 4);
  float* h2      = (float*)carve((size_t)N_NODES * 256 * 4);
  __hip_bfloat16* hbHi = (__hip_bfloat16*)carve((size_t)N_NODES * 256 * 2);
  __hip_bfloat16* hagg = (__hip_bfloat16*)carve((size_t)N_NODES * 256 * 2);
  __hip_bfloat16* H1   = (__hip_bfloat16*)carve((size_t)N_NODES * 256 * 2);
  __hip_bfloat16* feat = (__hip_bfloat16*)carve((size_t)N_NODES * 768 * 2);

  prep_csr<<<9186, 256, 0, stream>>>(mlp_W1, mlp_W2, att_W1, pred_W, mask_W1, x, graph,
                                     Wt1, Wt2, attHi, attLo, predWt, maskHi, maskLo,
                                     hbHi, stats, col_idx, deg);
  emlp2_kernel<<<256, 256, 0, stream>>>(x, attHi, attLo, att_b1, att_W2, att_b2,
                                        maskHi, maskLo, mask_b1, mask_W2, mask_b2,
                                        evec, maskL);
  for (int l = 0; l < 3; ++l) {
    agg4<<<N_NODES / 4, 256, 0, stream>>>(hbHi, evec, col_idx, deg, hagg);
    gemm_bf16<true, true, false><<<dim3(128, 4), 256, 0, stream>>>(
        hagg, Wt1 + (size_t)l * 65536, mlp_b1 + l * 256, H1, 256, 256, nullptr);
    gemm_bf16<false, false, true><<<dim3(128, 4), 256, 0, stream>>>(
        H1, Wt2 + (size_t)l * 65536, mlp_b2 + l * 256, h2, 256, 256, stats + l * 512);
    if (l < 2) {
      bn_emlp<<<256, 256, 0, stream>>>(h2, stats + l * 512, bn_g + l * 256, bn_b + l * 256,
                                       maskL + l * N_NODES,
                                       attHi + (size_t)(l + 1) * 16384,
                                       attLo + (size_t)(l + 1) * 16384,
                                       att_b1 + (l + 1) * 64, att_W2 + (l + 1) * 64,
                                       att_b2 + (l + 1),
                                       hbHi, feat, l, evec);
    } else {
      layer_y3<<<512, 256, 0, stream>>>(h2, stats + l * 512, bn_g + l * 256, bn_b + l * 256,
                                        maskL + l * N_NODES, feat, predWt, pred_b, out);
    }
  }
}